// Round 20
// baseline (2162.395 us; speedup 1.0000x reference)
//
#include <hip/hip_runtime.h>

typedef unsigned short u16;
typedef unsigned char u8;
typedef unsigned int u32;
typedef long i64;
typedef __attribute__((ext_vector_type(4))) float f32x4;
typedef __attribute__((ext_vector_type(4))) int i32x4;

#define TSTEPS 50
#define BB 256
#define II 1024
#define HH 4096
#define LL 10
#define NPLANE ((size_t)BB*HH)
#define HB ((size_t)HH*BB)
#define IB ((size_t)II*BB)
#define TC 10         // chunk length (5 chunk dispatches)
#define NSLOT 11      // ring slots
#define QSCALE 5.0e6f // i8 quantization scale for u / tp_i
#define WSCALE 64.0f  // fp8 weight pre-scale (undone in epilogue)

__device__ __forceinline__ u16 f2bf(float f){
  u32 u = __float_as_uint(f);
  u += 0x7fffu + ((u >> 16) & 1u);
  return (u16)(u >> 16);
}
__device__ __forceinline__ float bf2f(u16 u){ return __uint_as_float(((u32)u) << 16); }
__device__ __forceinline__ int wrapslot(int s){ return s >= NSLOT ? s - NSLOT : s; }

// f32 (>=0, < 448) -> OCP e4m3fn, RNE, with subnormals.
__device__ __forceinline__ u8 f2fp8(float v){
  if (v < 0.0009765625f) return 0;
  if (v < 0.015625f) return (u8)__float2int_rn(v * 512.f);
  u32 b = __float_as_uint(v);
  b += 0x7ffffu + ((b >> 20) & 1u);
  int e = (int)((b >> 23) & 255) - 120;
  u32 m = (b >> 20) & 7u;
  return (u8)((e << 3) | m);
}

__device__ __forceinline__ void async_cp16(const void* g, void* l){
  auto gp = (const __attribute__((address_space(1))) void*)(unsigned long long)(g);
  auto lp = (__attribute__((address_space(3))) void*)(unsigned int)(unsigned long long)(l);
  __builtin_amdgcn_global_load_lds(gp, lp, 16, 0, 0);
}

// ---------------- prep body: x->fp8 + tp_i filter + i8 transposed slab ------
__device__ __forceinline__ void prep_body(
    const float* __restrict__ x, int t, int i0, int b0, int tid,
    u8* __restrict__ xb_buf, float* __restrict__ tpi,
    u8* __restrict__ tpi01s, int slot,
    u8* ls)
{
  u8 vp[4];
#pragma unroll
  for (int e=0;e<4;++e){
    int f = e*256 + tid;
    int il = f & 63, bl = f >> 6;
    size_t ix = ((size_t)t*BB + b0+bl)*II + i0 + il;
    size_t is = (size_t)(b0+bl)*II + i0 + il;
    float xv = x[ix];
    xb_buf[is] = (xv != 0.f) ? 0x38 : 0;     // fp8 1.0 / 0.0 (binary exact)
    float p = tpi[is]; p += 0.0005f*(0.001f*xv - p); tpi[is] = p;
    vp[e] = (u8)__float2int_rn(p * QSCALE);
  }
#pragma unroll
  for (int e=0;e<4;++e){
    int f=e*256+tid; int il=f&63, bl=f>>6;
    ls[il*17+bl] = vp[e];
  }
  __syncthreads();
#pragma unroll
  for (int e=0;e<4;++e){
    int f=e*256+tid; int bl=f&15, il=f>>4;
    size_t oi = (size_t)slot*IB + (size_t)(i0+il)*BB + b0 + bl;
    tpi01s[oi] = ls[il*17+bl];
  }
}

// ---------------- fused forward GEMM (K=5120 fp8) + LIF + ring writes -------
// blocks 0..255: 64(batch)x64(H) tile, full K = [x(1024) | z_old(4096)],
//   epilogue applies LIF in f32 and writes v,iS,u,sc,zb_new + transposed rings.
// blocks 256..511: prep for t+1 (independent of GEMM output; xb/zb dbuf'd).
__global__ void __launch_bounds__(256) fwd_step(
    const u8* __restrict__ xbR, const u8* __restrict__ wib,
    const u8* __restrict__ zbR, const u8* __restrict__ wrb,
    u16* __restrict__ v, u16* __restrict__ iS, u8* __restrict__ sc,
    u16* __restrict__ u,
    u8* __restrict__ zbW, u8* __restrict__ zRing, u8* __restrict__ uRing,
    int slotZ,
    const float* __restrict__ x, int tnext, int do_prep,
    u8* __restrict__ xbW, float* __restrict__ tpi,
    u8* __restrict__ tpi01s, int slotP)
{
  __shared__ u8 lsA[2][64*64];    // 4KB per buf
  __shared__ u8 lsB[2][64*64];
  __shared__ u8 tT[2][64*65];     // transpose staging (z, u)
  const int tid = threadIdx.x, lane = tid & 63, wid = tid >> 6;
  const int bid = blockIdx.x;

  if (bid >= 256){
    if (!do_prep) return;
    int r = bid - 256;
    prep_body(x, tnext, (r & 15)*64, (r >> 4)*16, tid,
              xbW, tpi, tpi01s, slotP, tT[0]);   // reuse LDS
    return;
  }

  const int wm = wid & 1, wn = wid >> 1;   // 2x2 waves, 32x32 per wave
  int xcd = bid & 7;
  int local = bid >> 3;                 // 0..31
  int n0 = xcd*512 + (local & 7)*64;    // XCD-owned H slice (weights L2-hot)
  int m0 = (local >> 3)*64;             // batch tile

  const int lrow = lane >> 2;
  const int lcb  = (lane & 3) << 4;

  auto STAGE = [&](int buf, int kt){
    const u8* __restrict__ A; const u8* __restrict__ B;
    int lda, k0;
    if (kt < 16){ A = xbR; B = wib; lda = II; k0 = kt << 6; }
    else        { A = zbR; B = wrb; lda = HH; k0 = (kt-16) << 6; }
    int q = wid;
    int row = q*16 + lrow;
    int cb = lcb ^ (((row >> 1) & 3) << 4);
    async_cp16(A + (size_t)(m0 + row)*lda + k0 + cb, (char*)lsA[buf] + q*1024);
    async_cp16(B + (size_t)(n0 + row)*lda + k0 + cb, (char*)lsB[buf] + q*1024);
  };

  f32x4 acc[2][2];
#pragma unroll
  for (int a=0;a<2;++a)
#pragma unroll
    for (int b=0;b<2;++b) acc[a][b] = f32x4{0.f,0.f,0.f,0.f};

  const int g16 = lane >> 4;
  STAGE(0, 0);
#pragma unroll 1
  for (int kt = 0; kt < 80; ++kt){
    int cur = kt & 1;
    if (kt < 79){
      STAGE(cur ^ 1, kt+1);                            // 2 loads in flight
      asm volatile("s_waitcnt vmcnt(2)" ::: "memory"); // cur buf landed
    } else {
      asm volatile("s_waitcnt vmcnt(0)" ::: "memory");
    }
    __builtin_amdgcn_s_barrier();
#pragma unroll
    for (int kk = 0; kk < 2; ++kk){
      int unit = kk*2 + (g16 >> 1);
      int lo8  = (g16 & 1) << 3;
      i64 af[2], bfr[2];
#pragma unroll
      for (int fm=0; fm<2; ++fm){
        int ra = wm*32 + fm*16 + (lane & 15);
        af[fm] = *(const i64*)((const char*)lsA[cur] + ra*64 +
                               (((unit ^ ((ra >> 1) & 3)) << 4) + lo8));
      }
#pragma unroll
      for (int fn=0; fn<2; ++fn){
        int rb = wn*32 + fn*16 + (lane & 15);
        bfr[fn] = *(const i64*)((const char*)lsB[cur] + rb*64 +
                                (((unit ^ ((rb >> 1) & 3)) << 4) + lo8));
      }
#pragma unroll
      for (int fm=0; fm<2; ++fm)
#pragma unroll
        for (int fn=0; fn<2; ++fn)
          acc[fm][fn] = __builtin_amdgcn_mfma_f32_16x16x32_fp8_fp8(af[fm], bfr[fn], acc[fm][fn], 0, 0, 0);
    }
    __builtin_amdgcn_s_barrier();
  }

  // ---- LIF epilogue (f32 in_cur, exact vs. prior bf16-partial sum) ----
#pragma unroll
  for (int fm=0; fm<2; ++fm)
#pragma unroll
    for (int fn=0; fn<2; ++fn)
#pragma unroll
      for (int r=0; r<4; ++r){
        int rloc = wm*32 + fm*16 + (g16 << 2) + r;       // batch-local
        int cloc = wn*32 + fn*16 + (lane & 15);          // h-local
        size_t idx = (size_t)(m0 + rloc)*HH + n0 + cloc;
        float ic = acc[fm][fn][r] * (1.0f/WSCALE);
        float vv = bf2f(v[idx]), ii = bf2f(iS[idx]);
        float vdec = vv + 0.05f*((0.0f - vv) + ii);
        float idec = ii - 0.1f*ii;
        bool spk = (vdec >= 0.5f);
        float z = spk ? 1.0f : 0.0f;
        v[idx] = spk ? (u16)0 : f2bf(vdec);
        iS[idx] = f2bf(idec + ic);
        float uu = bf2f(u[idx]); uu += 0.0005f*(0.001f*z - uu); u[idx] = f2bf(uu);
        sc[idx] = (u8)(sc[idx] + (spk ? 1 : 0));
        zbW[idx] = spk ? 0x38 : 0;                       // fp8 1.0/0.0
        tT[0][cloc*65 + rloc] = spk ? 1 : 0;
        tT[1][cloc*65 + rloc] = (u8)__float2int_rn(uu * QSCALE);
      }
  __syncthreads();
#pragma unroll
  for (int e=0; e<16; ++e){
    int f = e*256 + tid;
    int bl = f & 63, hl = f >> 6;
    size_t oi = (size_t)slotZ*HB + (size_t)(n0 + hl)*BB + m0 + bl;
    zRing[oi] = tT[0][hl*65 + bl];
    uRing[oi] = tT[1][hl*65 + bl];
  }
}

// ---------------- chunked deferred STDP GEMM (i8, ETA_PLUS only) ------------
// TC=10: 5 dispatches. Epilogue in uniform branches (R18 proven).
__global__ void __launch_bounds__(512) gemm_chunk(
    const u8* __restrict__ zRing, const u8* __restrict__ uRing,
    const u8* __restrict__ tpi01s,
    int s0, int first, int lastd,
    float* __restrict__ o_wrec, float* __restrict__ o_win,
    const float* __restrict__ w0rec, const float* __restrict__ w0in,
    float scale)
{
  __shared__ u8 lsA[2][256*64];
  __shared__ u8 lsB[2][256*64];
  const int tid = threadIdx.x, lane = tid & 63, wid = tid >> 6;
  const int xcd = blockIdx.x & 7;
  const int local = blockIdx.x >> 3;
  const int g16 = lane >> 4;
  const int lrow = lane >> 2;
  const int lcb  = (lane & 3) << 4;

  if (local < 32){
    const int wm = wid & 1, wn = wid >> 1;
    int tm = (xcd >> 1)*4 + (local & 3);
    int tn = (xcd & 1)*8 + (local >> 2);
    int m0 = tm*256, n0 = tn*256;

    int offA[2], offB[2], ldso[2];
#pragma unroll
    for (int c=0;c<2;++c){
      int q = c*8 + wid;
      int row = q*16 + lrow;
      int cb = lcb ^ (((row >> 1) & 3) << 4);
      offA[c] = (m0 + row)*BB + cb;
      offB[c] = (n0 + row)*BB + cb;
      ldso[c] = q*1024;
    }

    auto STAGE = [&](int buf, int idx){
      int j  = idx >> 2;
      int k0 = (idx & 3) << 6;
      int sA = wrapslot(s0 + j + 1);
      int sB = wrapslot(s0 + j);
      const u8* __restrict__ Aslab = zRing + (size_t)sA*HB;
      const u8* __restrict__ Bslab = uRing + (size_t)sB*HB;
#pragma unroll
      for (int c=0;c<2;++c){
        async_cp16(Aslab + offA[c] + k0, (char*)lsA[buf] + ldso[c]);
        async_cp16(Bslab + offB[c] + k0, (char*)lsB[buf] + ldso[c]);
      }
    };

    i32x4 acc[8][4];
#pragma unroll
    for (int a=0;a<8;++a)
#pragma unroll
      for (int b=0;b<4;++b) acc[a][b] = i32x4{0,0,0,0};

    STAGE(0, 0);
#pragma unroll 1
    for (int idx = 0; idx < 4*TC; ++idx){
      int cur = idx & 1;
      if (idx < 4*TC-1){
        STAGE(cur ^ 1, idx+1);
        asm volatile("s_waitcnt vmcnt(4)" ::: "memory");
      } else {
        asm volatile("s_waitcnt vmcnt(0)" ::: "memory");
      }
      __builtin_amdgcn_s_barrier();
      __builtin_amdgcn_s_setprio(1);
      i32x4 bfr[4];
#pragma unroll
      for (int fn=0; fn<4; ++fn){
        int rb = wn*64 + fn*16 + (lane & 15);
        bfr[fn] = *(const i32x4*)((const char*)lsB[cur] + rb*64 + ((g16 ^ ((rb >> 1) & 3)) << 4));
      }
#pragma unroll
      for (int fm=0; fm<8; ++fm){
        int ra = wm*128 + fm*16 + (lane & 15);
        i32x4 af = *(const i32x4*)((const char*)lsA[cur] + ra*64 + ((g16 ^ ((ra >> 1) & 3)) << 4));
#pragma unroll
        for (int fn=0; fn<4; ++fn)
          acc[fm][fn] = __builtin_amdgcn_mfma_i32_16x16x64_i8(af, bfr[fn], acc[fm][fn], 0, 0, 0);
      }
      __builtin_amdgcn_s_setprio(0);
      __builtin_amdgcn_s_barrier();
    }

    if (lastd){
#pragma unroll
      for (int fm=0; fm<8; ++fm)
#pragma unroll
        for (int fn=0; fn<4; ++fn)
#pragma unroll
          for (int r=0; r<4; ++r){
            int row = m0 + wm*128 + fm*16 + ((lane >> 4) << 2) + r;
            int col = n0 + wn*64 + fn*16 + (lane & 15);
            size_t cidx = (size_t)row*HH + col;
            o_wrec[cidx] = w0rec[cidx] + scale*((float)acc[fm][fn][r] + o_wrec[cidx]);
          }
    } else if (first){
#pragma unroll
      for (int fm=0; fm<8; ++fm)
#pragma unroll
        for (int fn=0; fn<4; ++fn)
#pragma unroll
          for (int r=0; r<4; ++r){
            int row = m0 + wm*128 + fm*16 + ((lane >> 4) << 2) + r;
            int col = n0 + wn*64 + fn*16 + (lane & 15);
            o_wrec[(size_t)row*HH + col] = (float)acc[fm][fn][r];
          }
    } else {
#pragma unroll
      for (int fm=0; fm<8; ++fm)
#pragma unroll
        for (int fn=0; fn<4; ++fn)
#pragma unroll
          for (int r=0; r<4; ++r){
            int row = m0 + wm*128 + fm*16 + ((lane >> 4) << 2) + r;
            int col = n0 + wn*64 + fn*16 + (lane & 15);
            o_wrec[(size_t)row*HH + col] += (float)acc[fm][fn][r];
          }
    }
  } else {
    const int wm = wid & 1, wn = wid >> 1;
    int l2 = local - 32;
    int tm = (xcd >> 1)*8 + (l2 & 7);
    int tn = (xcd & 1)*4 + (l2 >> 3);
    int m0 = tm*128, n0 = tn*128;

    int offA, offB, ldso;
    {
      int q = wid;
      int row = q*16 + lrow;
      int cb = lcb ^ (((row >> 1) & 3) << 4);
      offA = (m0 + row)*BB + cb;
      offB = (n0 + row)*BB + cb;
      ldso = q*1024;
    }

    auto STAGE = [&](int buf, int idx){
      int j  = idx >> 2;
      int k0 = (idx & 3) << 6;
      int sA = wrapslot(s0 + j + 1);
      const u8* __restrict__ Aslab = zRing + (size_t)sA*HB;
      const u8* __restrict__ Bslab = tpi01s + (size_t)sA*IB;
      async_cp16(Aslab + offA + k0, (char*)lsA[buf] + ldso);
      async_cp16(Bslab + offB + k0, (char*)lsB[buf] + ldso);
    };

    i32x4 acc[4][2];
#pragma unroll
    for (int a=0;a<4;++a)
#pragma unroll
      for (int b=0;b<2;++b) acc[a][b] = i32x4{0,0,0,0};

    STAGE(0, 0);
#pragma unroll 1
    for (int idx = 0; idx < 4*TC; ++idx){
      int cur = idx & 1;
      if (idx < 4*TC-1){
        STAGE(cur ^ 1, idx+1);
        asm volatile("s_waitcnt vmcnt(2)" ::: "memory");
      } else {
        asm volatile("s_waitcnt vmcnt(0)" ::: "memory");
      }
      __builtin_amdgcn_s_barrier();
      __builtin_amdgcn_s_setprio(1);
      i32x4 bfr[2];
#pragma unroll
      for (int fn=0; fn<2; ++fn){
        int rb = wn*32 + fn*16 + (lane & 15);
        bfr[fn] = *(const i32x4*)((const char*)lsB[cur] + rb*64 + ((g16 ^ ((rb >> 1) & 3)) << 4));
      }
#pragma unroll
      for (int fm=0; fm<4; ++fm){
        int ra = wm*64 + fm*16 + (lane & 15);
        i32x4 af = *(const i32x4*)((const char*)lsA[cur] + ra*64 + ((g16 ^ ((ra >> 1) & 3)) << 4));
#pragma unroll
        for (int fn=0; fn<2; ++fn)
          acc[fm][fn] = __builtin_amdgcn_mfma_i32_16x16x64_i8(af, bfr[fn], acc[fm][fn], 0, 0, 0);
      }
      __builtin_amdgcn_s_setprio(0);
      __builtin_amdgcn_s_barrier();
    }

    if (lastd){
#pragma unroll
      for (int fm=0; fm<4; ++fm)
#pragma unroll
        for (int fn=0; fn<2; ++fn)
#pragma unroll
          for (int r=0; r<4; ++r){
            int row = m0 + wm*64 + fm*16 + ((lane >> 4) << 2) + r;
            int col = n0 + wn*32 + fn*16 + (lane & 15);
            size_t cidx = (size_t)row*II + col;
            o_win[cidx] = w0in[cidx] + scale*((float)acc[fm][fn][r] + o_win[cidx]);
          }
    } else if (first){
#pragma unroll
      for (int fm=0; fm<4; ++fm)
#pragma unroll
        for (int fn=0; fn<2; ++fn)
#pragma unroll
          for (int r=0; r<4; ++r){
            int row = m0 + wm*64 + fm*16 + ((lane >> 4) << 2) + r;
            int col = n0 + wn*32 + fn*16 + (lane & 15);
            o_win[(size_t)row*II + col] = (float)acc[fm][fn][r];
          }
    } else {
#pragma unroll
      for (int fm=0; fm<4; ++fm)
#pragma unroll
        for (int fn=0; fn<2; ++fn)
#pragma unroll
          for (int r=0; r<4; ++r){
            int row = m0 + wm*64 + fm*16 + ((lane >> 4) << 2) + r;
            int col = n0 + wn*32 + fn*16 + (lane & 15);
            o_win[(size_t)row*II + col] += (float)acc[fm][fn][r];
          }
    }
  }
}

__global__ void __launch_bounds__(256) prep0(
    const float* __restrict__ x, u8* __restrict__ xb_buf,
    float* __restrict__ tpi, u8* __restrict__ tpi01s)
{
  __shared__ u8 ls[64*17];
  int bid = blockIdx.x;
  prep_body(x, 0, (bid & 15)*64, (bid >> 4)*16, threadIdx.x,
            xb_buf, tpi, tpi01s, 1, ls);
}

// ---------------- casts and finalize ----------------------------------------
__global__ void __launch_bounds__(256) cast_fp8(const f32x4* __restrict__ w0,
                                                u32* __restrict__ wb, long long n4){
  long long i = (long long)blockIdx.x*blockDim.x + threadIdx.x;
  long long stride = (long long)gridDim.x*blockDim.x;
  for (; i < n4; i += stride){
    f32x4 vv = w0[i];
    u32 o = (u32)f2fp8(vv[0]*WSCALE)
          | ((u32)f2fp8(vv[1]*WSCALE) << 8)
          | ((u32)f2fp8(vv[2]*WSCALE) << 16)
          | ((u32)f2fp8(vv[3]*WSCALE) << 24);
    wb[i] = o;
  }
}

__global__ void __launch_bounds__(256) fin_logits(const u8* __restrict__ sc,
                                                  float* __restrict__ logits, float* __restrict__ total){
  __shared__ float bins[LL];
  const int tid = threadIdx.x;
  const int b = blockIdx.x;
  if (tid < LL) bins[tid] = 0.f;
  __syncthreads();
#pragma unroll
  for (int e=0;e<16;++e){
    int h = e*256 + tid;
    float vv = (float)sc[(size_t)b*HH + h];
    int a = h/409; if (a > 9) a = 9;
    atomicAdd(&bins[a], vv);
  }
  __syncthreads();
  if (tid < LL){
    float cnt = (tid==9) ? 415.f : 409.f;
    logits[b*LL + tid] = bins[tid] / (50.f * cnt);
  }
  if (tid == 0){
    float s = 0.f;
    for (int l=0;l<LL;++l) s += bins[l];
    atomicAdd(total, s);
  }
}

__global__ void __launch_bounds__(256) fin_spikecnt(const u8* __restrict__ sc,
                                                    const int* __restrict__ label, float* __restrict__ out){
  int h = blockIdx.x*256 + threadIdx.x;
  int bs = blockIdx.y*32;
  float acc[LL];
#pragma unroll
  for (int j=0;j<LL;++j) acc[j] = 0.f;
  for (int b=bs; b<bs+32; ++b){
    int l = label[b];
    float vv = (float)sc[(size_t)b*HH + h];
#pragma unroll
    for (int j=0;j<LL;++j) acc[j] += (j==l) ? vv : 0.f;
  }
#pragma unroll
  for (int j=0;j<LL;++j)
    if (acc[j] != 0.f) atomicAdd(&out[(size_t)j*HH + h], acc[j]);
}

__global__ void __launch_bounds__(256) fin_labelcnt(const int* __restrict__ label, float* __restrict__ out){
  __shared__ int bins[LL];
  const int tid = threadIdx.x;
  if (tid < LL) bins[tid] = 0;
  __syncthreads();
  atomicAdd(&bins[label[tid]], 1);
  __syncthreads();
  if (tid < LL) out[tid] = 50.f * (float)bins[tid];
}

extern "C" void kernel_launch(void* const* d_in, const int* in_sizes, int n_in,
                              void* d_out, int out_size, void* d_ws, size_t ws_size,
                              hipStream_t stream)
{
  (void)in_sizes; (void)n_in; (void)out_size; (void)ws_size;
  const float* x      = (const float*)d_in[0];
  const int*   label  = (const int*)d_in[1];
  const float* w_in0  = (const float*)d_in[2];
  const float* w_rec0 = (const float*)d_in[3];

  float* out      = (float*)d_out;
  float* o_logits = out;                            // 2560
  float* o_total  = out + 2560;                     // 1
  float* o_win    = out + 2561;                     // H*I f32 accumulator -> final
  float* o_wrec   = o_win + (size_t)HH*II;          // H*H f32 accumulator -> final
  float* o_sc     = o_wrec + (size_t)HH*HH;         // L*H
  float* o_lc     = o_sc + (size_t)LL*HH;           // L

  char* cur = (char*)d_ws;
  auto alloc = [&](size_t bytes)->char*{ char* p = cur; cur += (bytes + 255) & ~(size_t)255; return p; };
  u8*    wib    = (u8*)   alloc((size_t)HH*II);          //  4.2 MB
  u8*    wrb    = (u8*)   alloc((size_t)HH*HH);          // 16.8 MB
  u16*   v      = (u16*)  alloc(NPLANE*2);               //  2.1 (bf16)
  u16*   iS     = (u16*)  alloc(NPLANE*2);               //  2.1 (bf16)
  u8*    sc     = (u8*)   alloc(NPLANE);                 //  1.05
  u16*   u      = (u16*)  alloc(NPLANE*2);               //  2.1 (bf16)
  u8*    zb0    = (u8*)   alloc(NPLANE);                 //  1.05 (dbuf)
  u8*    zb1    = (u8*)   alloc(NPLANE);                 //  1.05
  u8*    xb0    = (u8*)   alloc((size_t)BB*II);          //  0.26 (dbuf)
  u8*    xb1    = (u8*)   alloc((size_t)BB*II);          //  0.26
  float* tpi    = (float*)alloc((size_t)BB*II*4);        //  1.0
  u8*    zRing  = (u8*)   alloc((size_t)NSLOT*HB);       // 11.5
  u8*    uRing  = (u8*)   alloc((size_t)NSLOT*HB);       // 11.5
  u8*    tpi01s = (u8*)   alloc((size_t)NSLOT*IB);       //  2.9
                                                         // total ~58 MB
  u8* zb[2] = {zb0, zb1};
  u8* xb[2] = {xb0, xb1};

  hipMemsetAsync(v,     0, NPLANE*2, stream);
  hipMemsetAsync(iS,    0, NPLANE*2, stream);
  hipMemsetAsync(sc,    0, NPLANE, stream);
  hipMemsetAsync(u,     0, NPLANE*2, stream);
  hipMemsetAsync(zb0,   0, NPLANE, stream);
  hipMemsetAsync(zb1,   0, NPLANE, stream);
  hipMemsetAsync(tpi,   0, (size_t)BB*II*4, stream);
  hipMemsetAsync(zRing, 0, HB, stream);                  // slot 0 = z(0) = 0
  hipMemsetAsync(uRing, 0, HB, stream);                  // slot 0 = u(0) = 0
  hipMemsetAsync(o_total, 0, 4, stream);
  hipMemsetAsync(o_sc,  0, (size_t)LL*HH*4, stream);

  cast_fp8<<<1024, 256, 0, stream>>>((const f32x4*)w_in0,  (u32*)wib, (long long)HH*II/4);
  cast_fp8<<<2048, 256, 0, stream>>>((const f32x4*)w_rec0, (u32*)wrb, (long long)HH*HH/4);
  prep0<<<256, 256, 0, stream>>>(x, xb[0], tpi, tpi01s);

  for (int t = 0; t < TSTEPS; ++t){
    fwd_step<<<512, 256, 0, stream>>>(
        xb[t & 1], wib, zb[t & 1], wrb,
        v, iS, sc, u,
        zb[(t+1) & 1], zRing, uRing, (t+1) % NSLOT,
        x, t+1, (t < TSTEPS-1) ? 1 : 0,
        xb[(t+1) & 1], tpi, tpi01s, (t+2) % NSLOT);

    if ((t+1) % TC == 0){
      int s0 = (t+1-TC) % NSLOT;
      gemm_chunk<<<512, 512, 0, stream>>>(zRing, uRing, tpi01s,
                                          s0, (t+1 == TC) ? 1 : 0,
                                          (t+1 == TSTEPS) ? 1 : 0,
                                          o_wrec, o_win, w_rec0, w_in0,
                                          0.01f/QSCALE);
    }
  }

  fin_logits  <<<BB, 256, 0, stream>>>(sc, o_logits, o_total);
  fin_spikecnt<<<dim3(HH/256, 8), 256, 0, stream>>>(sc, label, o_sc);
  fin_labelcnt<<<1, 256, 0, stream>>>(label, o_lc);
}

// Round 21
// 1543.377 us; speedup vs baseline: 1.4011x; 1.4011x over previous
//
#include <hip/hip_runtime.h>

typedef unsigned short u16;
typedef unsigned char u8;
typedef unsigned int u32;
typedef long i64;
typedef __attribute__((ext_vector_type(4))) float f32x4;
typedef __attribute__((ext_vector_type(4))) int i32x4;

#define TSTEPS 50
#define BB 256
#define II 1024
#define HH 4096
#define LL 10
#define NPLANE ((size_t)BB*HH)
#define HB ((size_t)HH*BB)
#define IB ((size_t)II*BB)
#define TC 25         // chunk length (2 chunk dispatches, minimal C-RMW)
#define NSLOT 26      // ring slots
#define QSCALE 5.0e6f // i8 quantization scale for u / tp_i
#define WSCALE 64.0f  // fp8 weight pre-scale (undone in step_state)

__device__ __forceinline__ u16 f2bf(float f){
  u32 u = __float_as_uint(f);
  u += 0x7fffu + ((u >> 16) & 1u);
  return (u16)(u >> 16);
}
__device__ __forceinline__ float bf2f(u16 u){ return __uint_as_float(((u32)u) << 16); }
__device__ __forceinline__ int wrapslot(int s){ return s >= NSLOT ? s - NSLOT : s; }

// f32 (>=0, < 448) -> OCP e4m3fn, RNE, with subnormals.
__device__ __forceinline__ u8 f2fp8(float v){
  if (v < 0.0009765625f) return 0;
  if (v < 0.015625f) return (u8)__float2int_rn(v * 512.f);
  u32 b = __float_as_uint(v);
  b += 0x7ffffu + ((b >> 20) & 1u);
  int e = (int)((b >> 23) & 255) - 120;
  u32 m = (b >> 20) & 7u;
  return (u8)((e << 3) | m);
}

__device__ __forceinline__ void async_cp16(const void* g, void* l){
  auto gp = (const __attribute__((address_space(1))) void*)(unsigned long long)(g);
  auto lp = (__attribute__((address_space(3))) void*)(unsigned int)(unsigned long long)(l);
  __builtin_amdgcn_global_load_lds(gp, lp, 16, 0, 0);
}

// ---------------- forward: fp8, split-K over 5 planes of K=1024 -------------
// XCD-resident weights: each XCD owns one 512-wide H slice (all planes, all m)
// -> per-XCD weight set 2.6 MB < 4 MB L2, static across all 50 steps.
__global__ void __launch_bounds__(256) gemm_fwd(
    const u8* __restrict__ xbt, const u8* __restrict__ wib,
    const u8* __restrict__ zb,  const u8* __restrict__ wrb,
    u16* __restrict__ pbuf)
{
  __shared__ u8 lsA[2][64*64];
  __shared__ u8 lsB[2][128*64];
  const int tid = threadIdx.x, lane = tid & 63, wid = tid >> 6;
  const int wm = wid & 1, wn = wid >> 1;

  int bid = blockIdx.x;
  int xcd = bid & 7;
  int local = bid >> 3;                 // 0..79
  int n0 = xcd*512 + (local & 3)*128;   // XCD-owned H slice
  int rest = local >> 2;                // 0..19
  int z = rest % 5;
  int m0 = (rest / 5)*64;

  const u8* __restrict__ Ab; const u8* __restrict__ Bb;
  int lda, ldb, kbase;
  if (z == 0){ Ab = xbt; lda = II; Bb = wib; ldb = II; kbase = 0; }
  else       { Ab = zb;  lda = HH; Bb = wrb; ldb = HH; kbase = (z-1)*1024; }
  u16* __restrict__ C = pbuf + (size_t)z*NPLANE;

  const int lrow = lane >> 2;
  const int lcb  = (lane & 3) << 4;

  auto STAGE = [&](int buf, int k0){
    int kg = kbase + k0;
    {
      int q = wid;
      int row = q*16 + lrow;
      int cb = lcb ^ (((row >> 1) & 3) << 4);
      async_cp16(Ab + (size_t)(m0 + row)*lda + kg + cb, (char*)lsA[buf] + q*1024);
    }
#pragma unroll
    for (int c = 0; c < 2; ++c){
      int q = c*4 + wid;
      int row = q*16 + lrow;
      int cb = lcb ^ (((row >> 1) & 3) << 4);
      async_cp16(Bb + (size_t)(n0 + row)*ldb + kg + cb, (char*)lsB[buf] + q*1024);
    }
  };

  f32x4 acc[2][4];
#pragma unroll
  for (int a=0;a<2;++a)
#pragma unroll
    for (int b=0;b<4;++b) acc[a][b] = f32x4{0.f,0.f,0.f,0.f};

  const int g16 = lane >> 4;
  STAGE(0, 0);
#pragma unroll 1
  for (int kt = 0; kt < 16; ++kt){
    int cur = kt & 1;
    if (kt < 15){
      STAGE(cur ^ 1, (kt+1)*64);
      asm volatile("s_waitcnt vmcnt(3)" ::: "memory");
    } else {
      asm volatile("s_waitcnt vmcnt(0)" ::: "memory");
    }
    __builtin_amdgcn_s_barrier();
#pragma unroll
    for (int kk = 0; kk < 2; ++kk){
      int unit = kk*2 + (g16 >> 1);
      int lo8  = (g16 & 1) << 3;
      i64 af[2], bfr[4];
#pragma unroll
      for (int fm=0; fm<2; ++fm){
        int ra = wm*32 + fm*16 + (lane & 15);
        af[fm] = *(const i64*)((const char*)lsA[cur] + ra*64 +
                               (((unit ^ ((ra >> 1) & 3)) << 4) + lo8));
      }
#pragma unroll
      for (int fn=0; fn<4; ++fn){
        int rb = wn*64 + fn*16 + (lane & 15);
        bfr[fn] = *(const i64*)((const char*)lsB[cur] + rb*64 +
                                (((unit ^ ((rb >> 1) & 3)) << 4) + lo8));
      }
#pragma unroll
      for (int fm=0; fm<2; ++fm)
#pragma unroll
        for (int fn=0; fn<4; ++fn)
          acc[fm][fn] = __builtin_amdgcn_mfma_f32_16x16x32_fp8_fp8(af[fm], bfr[fn], acc[fm][fn], 0, 0, 0);
    }
    __builtin_amdgcn_s_barrier();
  }

#pragma unroll
  for (int fm=0; fm<2; ++fm)
#pragma unroll
    for (int fn=0; fn<4; ++fn)
#pragma unroll
      for (int r=0; r<4; ++r){
        int row = m0 + wm*32 + fm*16 + ((lane >> 4) << 2) + r;
        int col = n0 + wn*64 + fn*16 + (lane & 15);
        C[(size_t)row*HH + col] = f2bf(acc[fm][fn][r]);
      }
}

// ---------------- chunked deferred STDP GEMM (i8, ETA_PLUS only) ------------
// TC=25: 2 dispatches. Epilogue split into uniform branches (R18 proven):
// first: C = acc ; last: C = w0 + scale*(C + acc).
__global__ void __launch_bounds__(512) gemm_chunk(
    const u8* __restrict__ zRing, const u8* __restrict__ uRing,
    const u8* __restrict__ tpi01s,
    int s0, int first, int lastd,
    float* __restrict__ o_wrec, float* __restrict__ o_win,
    const float* __restrict__ w0rec, const float* __restrict__ w0in,
    float scale)
{
  __shared__ u8 lsA[2][256*64];
  __shared__ u8 lsB[2][256*64];
  const int tid = threadIdx.x, lane = tid & 63, wid = tid >> 6;
  const int xcd = blockIdx.x & 7;
  const int local = blockIdx.x >> 3;
  const int g16 = lane >> 4;
  const int lrow = lane >> 2;
  const int lcb  = (lane & 3) << 4;

  if (local < 32){
    const int wm = wid & 1, wn = wid >> 1;
    int tm = (xcd >> 1)*4 + (local & 3);
    int tn = (xcd & 1)*8 + (local >> 2);
    int m0 = tm*256, n0 = tn*256;

    int offA[2], offB[2], ldso[2];
#pragma unroll
    for (int c=0;c<2;++c){
      int q = c*8 + wid;
      int row = q*16 + lrow;
      int cb = lcb ^ (((row >> 1) & 3) << 4);
      offA[c] = (m0 + row)*BB + cb;
      offB[c] = (n0 + row)*BB + cb;
      ldso[c] = q*1024;
    }

    auto STAGE = [&](int buf, int idx){
      int j  = idx >> 2;
      int k0 = (idx & 3) << 6;
      int sA = wrapslot(s0 + j + 1);
      int sB = wrapslot(s0 + j);
      const u8* __restrict__ Aslab = zRing + (size_t)sA*HB;
      const u8* __restrict__ Bslab = uRing + (size_t)sB*HB;
#pragma unroll
      for (int c=0;c<2;++c){
        async_cp16(Aslab + offA[c] + k0, (char*)lsA[buf] + ldso[c]);
        async_cp16(Bslab + offB[c] + k0, (char*)lsB[buf] + ldso[c]);
      }
    };

    i32x4 acc[8][4];
#pragma unroll
    for (int a=0;a<8;++a)
#pragma unroll
      for (int b=0;b<4;++b) acc[a][b] = i32x4{0,0,0,0};

    STAGE(0, 0);
#pragma unroll 1
    for (int idx = 0; idx < 4*TC; ++idx){
      int cur = idx & 1;
      if (idx < 4*TC-1){
        STAGE(cur ^ 1, idx+1);
        asm volatile("s_waitcnt vmcnt(4)" ::: "memory");
      } else {
        asm volatile("s_waitcnt vmcnt(0)" ::: "memory");
      }
      __builtin_amdgcn_s_barrier();
      __builtin_amdgcn_s_setprio(1);
      i32x4 bfr[4];
#pragma unroll
      for (int fn=0; fn<4; ++fn){
        int rb = wn*64 + fn*16 + (lane & 15);
        bfr[fn] = *(const i32x4*)((const char*)lsB[cur] + rb*64 + ((g16 ^ ((rb >> 1) & 3)) << 4));
      }
#pragma unroll
      for (int fm=0; fm<8; ++fm){
        int ra = wm*128 + fm*16 + (lane & 15);
        i32x4 af = *(const i32x4*)((const char*)lsA[cur] + ra*64 + ((g16 ^ ((ra >> 1) & 3)) << 4));
#pragma unroll
        for (int fn=0; fn<4; ++fn)
          acc[fm][fn] = __builtin_amdgcn_mfma_i32_16x16x64_i8(af, bfr[fn], acc[fm][fn], 0, 0, 0);
      }
      __builtin_amdgcn_s_setprio(0);
      __builtin_amdgcn_s_barrier();
    }

    if (lastd){
#pragma unroll
      for (int fm=0; fm<8; ++fm)
#pragma unroll
        for (int fn=0; fn<4; ++fn)
#pragma unroll
          for (int r=0; r<4; ++r){
            int row = m0 + wm*128 + fm*16 + ((lane >> 4) << 2) + r;
            int col = n0 + wn*64 + fn*16 + (lane & 15);
            size_t cidx = (size_t)row*HH + col;
            o_wrec[cidx] = w0rec[cidx] + scale*((float)acc[fm][fn][r] + o_wrec[cidx]);
          }
    } else if (first){
#pragma unroll
      for (int fm=0; fm<8; ++fm)
#pragma unroll
        for (int fn=0; fn<4; ++fn)
#pragma unroll
          for (int r=0; r<4; ++r){
            int row = m0 + wm*128 + fm*16 + ((lane >> 4) << 2) + r;
            int col = n0 + wn*64 + fn*16 + (lane & 15);
            o_wrec[(size_t)row*HH + col] = (float)acc[fm][fn][r];
          }
    } else {
#pragma unroll
      for (int fm=0; fm<8; ++fm)
#pragma unroll
        for (int fn=0; fn<4; ++fn)
#pragma unroll
          for (int r=0; r<4; ++r){
            int row = m0 + wm*128 + fm*16 + ((lane >> 4) << 2) + r;
            int col = n0 + wn*64 + fn*16 + (lane & 15);
            o_wrec[(size_t)row*HH + col] += (float)acc[fm][fn][r];
          }
    }
  } else {
    const int wm = wid & 1, wn = wid >> 1;
    int l2 = local - 32;
    int tm = (xcd >> 1)*8 + (l2 & 7);
    int tn = (xcd & 1)*4 + (l2 >> 3);
    int m0 = tm*128, n0 = tn*128;

    int offA, offB, ldso;
    {
      int q = wid;
      int row = q*16 + lrow;
      int cb = lcb ^ (((row >> 1) & 3) << 4);
      offA = (m0 + row)*BB + cb;
      offB = (n0 + row)*BB + cb;
      ldso = q*1024;
    }

    auto STAGE = [&](int buf, int idx){
      int j  = idx >> 2;
      int k0 = (idx & 3) << 6;
      int sA = wrapslot(s0 + j + 1);
      const u8* __restrict__ Aslab = zRing + (size_t)sA*HB;
      const u8* __restrict__ Bslab = tpi01s + (size_t)sA*IB;
      async_cp16(Aslab + offA + k0, (char*)lsA[buf] + ldso);
      async_cp16(Bslab + offB + k0, (char*)lsB[buf] + ldso);
    };

    i32x4 acc[4][2];
#pragma unroll
    for (int a=0;a<4;++a)
#pragma unroll
      for (int b=0;b<2;++b) acc[a][b] = i32x4{0,0,0,0};

    STAGE(0, 0);
#pragma unroll 1
    for (int idx = 0; idx < 4*TC; ++idx){
      int cur = idx & 1;
      if (idx < 4*TC-1){
        STAGE(cur ^ 1, idx+1);
        asm volatile("s_waitcnt vmcnt(2)" ::: "memory");
      } else {
        asm volatile("s_waitcnt vmcnt(0)" ::: "memory");
      }
      __builtin_amdgcn_s_barrier();
      __builtin_amdgcn_s_setprio(1);
      i32x4 bfr[2];
#pragma unroll
      for (int fn=0; fn<2; ++fn){
        int rb = wn*32 + fn*16 + (lane & 15);
        bfr[fn] = *(const i32x4*)((const char*)lsB[cur] + rb*64 + ((g16 ^ ((rb >> 1) & 3)) << 4));
      }
#pragma unroll
      for (int fm=0; fm<4; ++fm){
        int ra = wm*64 + fm*16 + (lane & 15);
        i32x4 af = *(const i32x4*)((const char*)lsA[cur] + ra*64 + ((g16 ^ ((ra >> 1) & 3)) << 4));
#pragma unroll
        for (int fn=0; fn<2; ++fn)
          acc[fm][fn] = __builtin_amdgcn_mfma_i32_16x16x64_i8(af, bfr[fn], acc[fm][fn], 0, 0, 0);
      }
      __builtin_amdgcn_s_setprio(0);
      __builtin_amdgcn_s_barrier();
    }

    if (lastd){
#pragma unroll
      for (int fm=0; fm<4; ++fm)
#pragma unroll
        for (int fn=0; fn<2; ++fn)
#pragma unroll
          for (int r=0; r<4; ++r){
            int row = m0 + wm*64 + fm*16 + ((lane >> 4) << 2) + r;
            int col = n0 + wn*32 + fn*16 + (lane & 15);
            size_t cidx = (size_t)row*II + col;
            o_win[cidx] = w0in[cidx] + scale*((float)acc[fm][fn][r] + o_win[cidx]);
          }
    } else if (first){
#pragma unroll
      for (int fm=0; fm<4; ++fm)
#pragma unroll
        for (int fn=0; fn<2; ++fn)
#pragma unroll
          for (int r=0; r<4; ++r){
            int row = m0 + wm*64 + fm*16 + ((lane >> 4) << 2) + r;
            int col = n0 + wn*32 + fn*16 + (lane & 15);
            o_win[(size_t)row*II + col] = (float)acc[fm][fn][r];
          }
    } else {
#pragma unroll
      for (int fm=0; fm<4; ++fm)
#pragma unroll
        for (int fn=0; fn<2; ++fn)
#pragma unroll
          for (int r=0; r<4; ++r){
            int row = m0 + wm*64 + fm*16 + ((lane >> 4) << 2) + r;
            int col = n0 + wn*32 + fn*16 + (lane & 15);
            o_win[(size_t)row*II + col] += (float)acc[fm][fn][r];
          }
    }
  }
}

// ---------------- prep body: x->fp8 + tp_i filter + i8 transposed slab ------
__device__ __forceinline__ void prep_body(
    const float* __restrict__ x, int t, int i0, int b0, int tid,
    u8* __restrict__ xb_buf, float* __restrict__ tpi,
    u8* __restrict__ tpi01s, int slot,
    u8* ls)
{
  u8 vp[4];
#pragma unroll
  for (int e=0;e<4;++e){
    int f = e*256 + tid;
    int il = f & 63, bl = f >> 6;
    size_t ix = ((size_t)t*BB + b0+bl)*II + i0 + il;
    size_t is = (size_t)(b0+bl)*II + i0 + il;
    float xv = x[ix];
    xb_buf[is] = (xv != 0.f) ? 0x38 : 0;     // fp8 1.0 / 0.0 (binary exact)
    float p = tpi[is]; p += 0.0005f*(0.001f*xv - p); tpi[is] = p;
    vp[e] = (u8)__float2int_rn(p * QSCALE);
  }
#pragma unroll
  for (int e=0;e<4;++e){
    int f=e*256+tid; int il=f&63, bl=f>>6;
    ls[il*17+bl] = vp[e];
  }
  __syncthreads();
#pragma unroll
  for (int e=0;e<4;++e){
    int f=e*256+tid; int bl=f&15, il=f>>4;
    size_t oi = (size_t)slot*IB + (size_t)(i0+il)*BB + b0 + bl;
    tpi01s[oi] = ls[il*17+bl];
  }
}

__global__ void __launch_bounds__(256) prep0(
    const float* __restrict__ x, u8* __restrict__ xb_buf,
    float* __restrict__ tpi, u8* __restrict__ tpi01s)
{
  __shared__ u8 ls[64*17];
  int bid = blockIdx.x;
  prep_body(x, 0, (bid & 15)*64, (bid >> 4)*16, threadIdx.x,
            xb_buf, tpi, tpi01s, 1, ls);
}

// ---------------- per-step state + i8 ring slabs + (merged) next-step prep --
__global__ void __launch_bounds__(256) step_state(
    const u16* __restrict__ pbuf,
    float* __restrict__ v, float* __restrict__ iS, u8* __restrict__ sc,
    u16* __restrict__ u,
    u8* __restrict__ zb, u8* __restrict__ zRing, u8* __restrict__ uRing,
    int slotZ,
    const float* __restrict__ x, int tnext, int do_prep,
    u8* __restrict__ xb_buf, float* __restrict__ tpi,
    u8* __restrict__ tpi01s, int slotP)
{
  __shared__ u8 ls[2][64*17];
  const int tid = threadIdx.x;
  const int bid = blockIdx.x;

  if (bid < 1024){
    const int h0 = (bid & 63) * 64;
    const int b0 = (bid >> 6) * 16;
    u8 vz[4], vu[4];
#pragma unroll
    for (int e=0;e<4;++e){
      int f = e*256 + tid;
      int hl = f & 63, bl = f >> 6;
      size_t idx = (size_t)(b0+bl)*HH + h0 + hl;
      float ic = (bf2f(pbuf[idx]) + bf2f(pbuf[idx + NPLANE]) + bf2f(pbuf[idx + 2*NPLANE])
               +  bf2f(pbuf[idx + 3*NPLANE]) + bf2f(pbuf[idx + 4*NPLANE])) * (1.0f/WSCALE);
      float vv = v[idx], ii = iS[idx];
      float vdec = vv + 0.05f*((0.0f - vv) + ii);
      float idec = ii - 0.1f*ii;
      bool spk = (vdec >= 0.5f);
      float z = spk ? 1.0f : 0.0f;
      v[idx] = spk ? 0.0f : vdec;
      iS[idx] = idec + ic;
      float uu = bf2f(u[idx]); uu += 0.0005f*(0.001f*z - uu); u[idx] = f2bf(uu);
      sc[idx] = (u8)(sc[idx] + (spk ? 1 : 0));
      zb[idx] = spk ? 0x38 : 0;   // fp8 1.0/0.0
      vz[e] = spk ? 1 : 0;
      vu[e] = (u8)__float2int_rn(uu * QSCALE);
    }
#pragma unroll
    for (int e=0;e<4;++e){
      int f=e*256+tid; int hl=f&63, bl=f>>6; int o = hl*17+bl;
      ls[0][o]=vz[e]; ls[1][o]=vu[e];
    }
    __syncthreads();
#pragma unroll
    for (int e=0;e<4;++e){
      int f=e*256+tid; int bl=f&15, hl=f>>4; int o=hl*17+bl;
      size_t oi = (size_t)slotZ*HB + (size_t)(h0+hl)*BB + b0 + bl;
      zRing[oi]=ls[0][o]; uRing[oi]=ls[1][o];
    }
  } else {
    if (!do_prep) return;
    int r = bid - 1024;
    prep_body(x, tnext, (r & 15)*64, (r >> 4)*16, tid,
              xb_buf, tpi, tpi01s, slotP, ls[0]);
  }
}

// ---------------- casts and finalize ----------------------------------------
__global__ void __launch_bounds__(256) cast_fp8(const f32x4* __restrict__ w0,
                                                u32* __restrict__ wb, long long n4){
  long long i = (long long)blockIdx.x*blockDim.x + threadIdx.x;
  long long stride = (long long)gridDim.x*blockDim.x;
  for (; i < n4; i += stride){
    f32x4 vv = w0[i];
    u32 o = (u32)f2fp8(vv[0]*WSCALE)
          | ((u32)f2fp8(vv[1]*WSCALE) << 8)
          | ((u32)f2fp8(vv[2]*WSCALE) << 16)
          | ((u32)f2fp8(vv[3]*WSCALE) << 24);
    wb[i] = o;
  }
}

__global__ void __launch_bounds__(256) fin_logits(const u8* __restrict__ sc,
                                                  float* __restrict__ logits, float* __restrict__ total){
  __shared__ float bins[LL];
  const int tid = threadIdx.x;
  const int b = blockIdx.x;
  if (tid < LL) bins[tid] = 0.f;
  __syncthreads();
#pragma unroll
  for (int e=0;e<16;++e){
    int h = e*256 + tid;
    float vv = (float)sc[(size_t)b*HH + h];
    int a = h/409; if (a > 9) a = 9;
    atomicAdd(&bins[a], vv);
  }
  __syncthreads();
  if (tid < LL){
    float cnt = (tid==9) ? 415.f : 409.f;
    logits[b*LL + tid] = bins[tid] / (50.f * cnt);
  }
  if (tid == 0){
    float s = 0.f;
    for (int l=0;l<LL;++l) s += bins[l];
    atomicAdd(total, s);
  }
}

__global__ void __launch_bounds__(256) fin_spikecnt(const u8* __restrict__ sc,
                                                    const int* __restrict__ label, float* __restrict__ out){
  int h = blockIdx.x*256 + threadIdx.x;
  int bs = blockIdx.y*32;
  float acc[LL];
#pragma unroll
  for (int j=0;j<LL;++j) acc[j] = 0.f;
  for (int b=bs; b<bs+32; ++b){
    int l = label[b];
    float vv = (float)sc[(size_t)b*HH + h];
#pragma unroll
    for (int j=0;j<LL;++j) acc[j] += (j==l) ? vv : 0.f;
  }
#pragma unroll
  for (int j=0;j<LL;++j)
    if (acc[j] != 0.f) atomicAdd(&out[(size_t)j*HH + h], acc[j]);
}

__global__ void __launch_bounds__(256) fin_labelcnt(const int* __restrict__ label, float* __restrict__ out){
  __shared__ int bins[LL];
  const int tid = threadIdx.x;
  if (tid < LL) bins[tid] = 0;
  __syncthreads();
  atomicAdd(&bins[label[tid]], 1);
  __syncthreads();
  if (tid < LL) out[tid] = 50.f * (float)bins[tid];
}

extern "C" void kernel_launch(void* const* d_in, const int* in_sizes, int n_in,
                              void* d_out, int out_size, void* d_ws, size_t ws_size,
                              hipStream_t stream)
{
  (void)in_sizes; (void)n_in; (void)out_size; (void)ws_size;
  const float* x      = (const float*)d_in[0];
  const int*   label  = (const int*)d_in[1];
  const float* w_in0  = (const float*)d_in[2];
  const float* w_rec0 = (const float*)d_in[3];

  float* out      = (float*)d_out;
  float* o_logits = out;                            // 2560
  float* o_total  = out + 2560;                     // 1
  float* o_win    = out + 2561;                     // H*I f32 accumulator -> final
  float* o_wrec   = o_win + (size_t)HH*II;          // H*H f32 accumulator -> final
  float* o_sc     = o_wrec + (size_t)HH*HH;         // L*H
  float* o_lc     = o_sc + (size_t)LL*HH;           // L

  char* cur = (char*)d_ws;
  auto alloc = [&](size_t bytes)->char*{ char* p = cur; cur += (bytes + 255) & ~(size_t)255; return p; };
  u8*    wib    = (u8*)   alloc((size_t)HH*II);          //  4.2 MB
  u8*    wrb    = (u8*)   alloc((size_t)HH*HH);          // 16.8 MB
  float* v      = (float*)alloc(NPLANE*4);               //  4.2
  float* iS     = (float*)alloc(NPLANE*4);               //  4.2
  u8*    sc     = (u8*)   alloc(NPLANE);                 //  1.05
  u16*   u      = (u16*)  alloc(NPLANE*2);               //  2.1 (bf16)
  u16*   pbuf   = (u16*)  alloc(5*NPLANE*2);             // 10.5 (bf16)
  u8*    zb     = (u8*)   alloc(NPLANE);                 //  1.05
  u8*    xb_buf = (u8*)   alloc((size_t)BB*II);          //  0.26
  float* tpi    = (float*)alloc((size_t)BB*II*4);        //  1.0
  u8*    zRing  = (u8*)   alloc((size_t)NSLOT*HB);       // 27.3
  u8*    uRing  = (u8*)   alloc((size_t)NSLOT*HB);       // 27.3
  u8*    tpi01s = (u8*)   alloc((size_t)NSLOT*IB);       //  6.8
                                                         // total ~107 MB

  hipMemsetAsync(v,     0, NPLANE*4, stream);
  hipMemsetAsync(iS,    0, NPLANE*4, stream);
  hipMemsetAsync(sc,    0, NPLANE, stream);
  hipMemsetAsync(u,     0, NPLANE*2, stream);
  hipMemsetAsync(zb,    0, NPLANE, stream);
  hipMemsetAsync(tpi,   0, (size_t)BB*II*4, stream);
  hipMemsetAsync(zRing, 0, HB, stream);                  // slot 0 = z(0) = 0
  hipMemsetAsync(uRing, 0, HB, stream);                  // slot 0 = u(0) = 0
  hipMemsetAsync(o_total, 0, 4, stream);
  hipMemsetAsync(o_sc,  0, (size_t)LL*HH*4, stream);

  cast_fp8<<<1024, 256, 0, stream>>>((const f32x4*)w_in0,  (u32*)wib, (long long)HH*II/4);
  cast_fp8<<<2048, 256, 0, stream>>>((const f32x4*)w_rec0, (u32*)wrb, (long long)HH*HH/4);
  prep0<<<256, 256, 0, stream>>>(x, xb_buf, tpi, tpi01s);

  for (int t = 0; t < TSTEPS; ++t){
    gemm_fwd<<<640, 256, 0, stream>>>(xb_buf, wib, zb, wrb, pbuf);

    step_state<<<1280, 256, 0, stream>>>(
        pbuf, v, iS, sc, u, zb, zRing, uRing, (t+1) % NSLOT,
        x, t+1, (t < TSTEPS-1) ? 1 : 0,
        xb_buf, tpi, tpi01s, (t+2) % NSLOT);

    if ((t+1) % TC == 0){
      int s0 = (t+1-TC) % NSLOT;
      gemm_chunk<<<512, 512, 0, stream>>>(zRing, uRing, tpi01s,
                                          s0, (t+1 == TC) ? 1 : 0,
                                          (t+1 == TSTEPS) ? 1 : 0,
                                          o_wrec, o_win, w_rec0, w_in0,
                                          0.01f/QSCALE);
    }
  }

  fin_logits  <<<BB, 256, 0, stream>>>(sc, o_logits, o_total);
  fin_spikecnt<<<dim3(HH/256, 8), 256, 0, stream>>>(sc, label, o_sc);
  fin_labelcnt<<<1, 256, 0, stream>>>(label, o_lc);
}